// Round 1
// baseline (147.174 us; speedup 1.0000x reference)
//
#include <hip/hip_runtime.h>
#include <hip/hip_fp16.h>

#define S_LEN 8192
#define T_LEN 8192
#define D_DIM 256
#define QBLK 128
#define KVBLK 64
#define TSPLIT 4
#define TCHUNK (T_LEN / TSPLIT)   // 2048
#define NKV (TCHUNK / KVBLK)      // 32
#define NQT (S_LEN / QBLK)        // 64

typedef _Float16 f16x8 __attribute__((ext_vector_type(8)));
typedef float f32x4 __attribute__((ext_vector_type(4)));

struct h4 { _Float16 h[4]; };  // 8 bytes

// ---------------- fp32 -> f16 convert (same layout) ----------------
__global__ __launch_bounds__(256) void cvt_kernel(const float* __restrict__ in,
                                                  _Float16* __restrict__ out, int n4) {
    int i = blockIdx.x * 256 + threadIdx.x;
    if (i < n4) {
        float4 v = ((const float4*)in)[i];
        h4 o;
        o.h[0] = (_Float16)v.x; o.h[1] = (_Float16)v.y;
        o.h[2] = (_Float16)v.z; o.h[3] = (_Float16)v.w;
        ((h4*)out)[i] = o;
    }
}

// ---------------- V [T][D] fp32 -> Vt [D][T] f16 (tiled transpose) ----------------
__global__ __launch_bounds__(256) void vt_kernel(const float* __restrict__ V,
                                                 _Float16* __restrict__ Vt) {
    __shared__ float tile[64][65];
    const int tb = blockIdx.x * 64;  // t base
    const int db = blockIdx.y * 64;  // d base
#pragma unroll
    for (int i = 0; i < 4; ++i) {
        int idx = i * 256 + threadIdx.x;      // 0..1023 float4s
        int tr = idx >> 4, c4 = idx & 15;
        float4 v = *(const float4*)(V + (size_t)(tb + tr) * D_DIM + db + c4 * 4);
        tile[tr][c4 * 4 + 0] = v.x;
        tile[tr][c4 * 4 + 1] = v.y;
        tile[tr][c4 * 4 + 2] = v.z;
        tile[tr][c4 * 4 + 3] = v.w;
    }
    __syncthreads();
#pragma unroll
    for (int i = 0; i < 4; ++i) {
        int idx = i * 256 + threadIdx.x;
        int dr = idx >> 4, t4 = idx & 15;
        h4 o;
        o.h[0] = (_Float16)tile[t4 * 4 + 0][dr];
        o.h[1] = (_Float16)tile[t4 * 4 + 1][dr];
        o.h[2] = (_Float16)tile[t4 * 4 + 2][dr];
        o.h[3] = (_Float16)tile[t4 * 4 + 3][dr];
        *(h4*)(Vt + (size_t)(db + dr) * T_LEN + tb + t4 * 4) = o;
    }
}

// ---------------- flash attention, one (qtile, split) per block ----------------
// 512 threads = 8 waves; wave owns 16 query rows. LDS 64KB:
//   sK  [64][256] f16, row stride 512B, 16B-chunk swizzle ck^=(r&7)
//   sVt [256][64] f16, row stride 128B, chunk swizzle tc^=(d&7)
//   sP  aliases first 16KB of sK (per-wave 2KB), used after post-QK barrier
__global__ __launch_bounds__(512, 2) void attn_kernel(
    const _Float16* __restrict__ Qh, const _Float16* __restrict__ Kh,
    const _Float16* __restrict__ Vt, float* __restrict__ Opart,
    float* __restrict__ ml) {
    __shared__ __align__(16) char smem[65536];
    const int tid = threadIdx.x;
    const int wave = tid >> 6, lane = tid & 63;
    const int g = lane >> 4, c = lane & 15;
    const int qtile = blockIdx.x, split = blockIdx.y;
    const int kv0 = split * TCHUNK;

    // ---- stage Q tile (f16, swizzled) into full 64KB, grab frags, release ----
    {
        const _Float16* Qb = Qh + (size_t)qtile * QBLK * D_DIM;
#pragma unroll
        for (int i = 0; i < 8; ++i) {
            int cl = i * 512 + tid;
            int r = cl >> 5, ck = cl & 31;
            uint4 v = *(const uint4*)(Qb + r * D_DIM + ck * 8);
            *(uint4*)(smem + r * 512 + ((ck ^ (r & 7)) << 4)) = v;
        }
    }
    __syncthreads();
    f16x8 qf[8];
    {
        int qr = wave * 16 + c;
#pragma unroll
        for (int ks = 0; ks < 8; ++ks) {
            int ck = ks * 4 + g;
            qf[ks] = *(const f16x8*)(smem + qr * 512 + ((ck ^ (qr & 7)) << 4));
        }
    }
    __syncthreads();

    char* sK = smem;
    char* sVt = smem + 32768;
    char* sP = smem + wave * 2048;  // wave-private, valid only after post-QK barrier

    f32x4 acc[16];
#pragma unroll
    for (int dt = 0; dt < 16; ++dt) acc[dt] = (f32x4){0.f, 0.f, 0.f, 0.f};
    float mrow[4] = {-1e30f, -1e30f, -1e30f, -1e30f};
    float lrow[4] = {0.f, 0.f, 0.f, 0.f};

    for (int kt = 0; kt < NKV; ++kt) {
        // ---- stage K tile ----
        const _Float16* Kb = Kh + (size_t)(kv0 + kt * KVBLK) * D_DIM;
#pragma unroll
        for (int i = 0; i < 4; ++i) {
            int cl = i * 512 + tid;
            int r = cl >> 5, ck = cl & 31;
            uint4 v = *(const uint4*)(Kb + r * D_DIM + ck * 8);
            *(uint4*)(sK + r * 512 + ((ck ^ (r & 7)) << 4)) = v;
        }
        // ---- stage Vt tile ----
        const _Float16* Vb = Vt + (size_t)(kv0 + kt * KVBLK);
#pragma unroll
        for (int i = 0; i < 4; ++i) {
            int cl = i * 512 + tid;
            int d = cl >> 3, tc = cl & 7;
            uint4 v = *(const uint4*)(Vb + (size_t)d * T_LEN + tc * 8);
            *(uint4*)(sVt + d * 128 + ((tc ^ (d & 7)) << 4)) = v;
        }
        __syncthreads();

        // ---- QK^T: S[16 rows][64 keys] per wave ----
        f32x4 s[4];
#pragma unroll
        for (int ct = 0; ct < 4; ++ct) s[ct] = (f32x4){0.f, 0.f, 0.f, 0.f};
#pragma unroll
        for (int ks = 0; ks < 8; ++ks) {
#pragma unroll
            for (int ct = 0; ct < 4; ++ct) {
                int kr = ct * 16 + c;
                f16x8 kf = *(const f16x8*)(sK + kr * 512 + (((ks * 4 + g) ^ (kr & 7)) << 4));
                s[ct] = __builtin_amdgcn_mfma_f32_16x16x32_f16(qf[ks], kf, s[ct], 0, 0, 0);
            }
        }
        __syncthreads();  // all waves done reading sK before sP overwrites it

        // ---- online softmax (rows live in C-layout: row=g*4+r, col=ct*16+c) ----
#pragma unroll
        for (int r = 0; r < 4; ++r) {
            float v = fmaxf(fmaxf(s[0][r], s[1][r]), fmaxf(s[2][r], s[3][r]));
#pragma unroll
            for (int off = 1; off < 16; off <<= 1) v = fmaxf(v, __shfl_xor(v, off));
            float mn = fmaxf(mrow[r], v);
            float sc = __expf(mrow[r] - mn);
            mrow[r] = mn;
            float rs = 0.f;
#pragma unroll
            for (int ct = 0; ct < 4; ++ct) {
                float p = __expf(s[ct][r] - mn);
                s[ct][r] = p;
                rs += p;
            }
#pragma unroll
            for (int off = 1; off < 16; off <<= 1) rs += __shfl_xor(rs, off);
            lrow[r] = lrow[r] * sc + rs;
#pragma unroll
            for (int dt = 0; dt < 16; ++dt) acc[dt][r] *= sc;
        }

        // ---- P (f32, C-layout) -> sP (f16, A-layout source), wave-private ----
#pragma unroll
        for (int ct = 0; ct < 4; ++ct)
#pragma unroll
            for (int r = 0; r < 4; ++r) {
                int row = g * 4 + r, col = ct * 16 + c;
                *(((_Float16*)(sP + row * 128 + (((col >> 3) ^ (row & 7)) << 4))) +
                  (col & 7)) = (_Float16)s[ct][r];
            }

        // ---- PV: acc[16 dtiles] += P[16][64] * V[64][256] ----
        f16x8 pf[2];
#pragma unroll
        for (int k2 = 0; k2 < 2; ++k2)
            pf[k2] = *(const f16x8*)(sP + c * 128 + (((k2 * 4 + g) ^ (c & 7)) << 4));
#pragma unroll
        for (int dt = 0; dt < 16; ++dt) {
#pragma unroll
            for (int k2 = 0; k2 < 2; ++k2) {
                int vr = dt * 16 + c;
                f16x8 vf = *(const f16x8*)(sVt + vr * 128 + (((k2 * 4 + g) ^ (vr & 7)) << 4));
                acc[dt] = __builtin_amdgcn_mfma_f32_16x16x32_f16(pf[k2], vf, acc[dt], 0, 0, 0);
            }
        }
        __syncthreads();  // PV + sP reads done before next tile staging
    }

    // ---- epilogue: unnormalized partial O + (m,l) ----
    float* Ob = Opart + (size_t)(qtile * TSPLIT + split) * QBLK * D_DIM;
#pragma unroll
    for (int dt = 0; dt < 16; ++dt)
#pragma unroll
        for (int r = 0; r < 4; ++r) {
            int row = wave * 16 + g * 4 + r, col = dt * 16 + c;
            Ob[row * D_DIM + col] = acc[dt][r];
        }
    if (c == 0) {
        float* mlb = ml + (size_t)((qtile * TSPLIT + split) * QBLK) * 2;
#pragma unroll
        for (int r = 0; r < 4; ++r) {
            int row = wave * 16 + g * 4 + r;
            mlb[row * 2 + 0] = mrow[r];
            mlb[row * 2 + 1] = lrow[r];
        }
    }
}

// ---------------- combine TSPLIT partials ----------------
__global__ __launch_bounds__(256) void combine_kernel(const float* __restrict__ Opart,
                                                      const float* __restrict__ ml,
                                                      float* __restrict__ out) {
    int r = blockIdx.x;
    int qtile = r >> 7, rl = r & 127;
    int d = threadIdx.x;
    float m[TSPLIT], l[TSPLIT];
    float M = -1e30f;
#pragma unroll
    for (int s = 0; s < TSPLIT; ++s) {
        const float* mlb = ml + (size_t)((qtile * TSPLIT + s) * QBLK + rl) * 2;
        m[s] = mlb[0];
        l[s] = mlb[1];
        M = fmaxf(M, m[s]);
    }
    float num = 0.f, den = 0.f;
#pragma unroll
    for (int s = 0; s < TSPLIT; ++s) {
        float w = __expf(m[s] - M);
        num += w * Opart[((size_t)(qtile * TSPLIT + s) * QBLK + rl) * D_DIM + d];
        den += w * l[s];
    }
    out[(size_t)r * D_DIM + d] = num / den;
}

extern "C" void kernel_launch(void* const* d_in, const int* in_sizes, int n_in,
                              void* d_out, int out_size, void* d_ws, size_t ws_size,
                              hipStream_t stream) {
    const float* Q = (const float*)d_in[0];
    const float* K = (const float*)d_in[1];
    const float* V = (const float*)d_in[2];
    float* out = (float*)d_out;
    char* ws = (char*)d_ws;

    _Float16* Qh = (_Float16*)ws;                  // 4MB
    _Float16* Kh = (_Float16*)(ws + (4 << 20));    // 4MB
    _Float16* Vt = (_Float16*)(ws + (8 << 20));    // 4MB  [D][T]
    float* Opart = (float*)(ws + (12 << 20));      // 32MB
    float* ml = (float*)(ws + (44 << 20));         // 256KB

    const int n4 = S_LEN * D_DIM / 4;  // 524288 float4s
    cvt_kernel<<<n4 / 256, 256, 0, stream>>>(Q, Qh, n4);
    cvt_kernel<<<n4 / 256, 256, 0, stream>>>(K, Kh, n4);
    dim3 tg(T_LEN / 64, D_DIM / 64);
    vt_kernel<<<tg, 256, 0, stream>>>(V, Vt);
    dim3 ag(NQT, TSPLIT);
    attn_kernel<<<ag, 512, 0, stream>>>(Qh, Kh, Vt, Opart, ml);
    combine_kernel<<<S_LEN, 256, 0, stream>>>(Opart, ml, out);
}